// Round 9
// baseline (327.203 us; speedup 1.0000x reference)
//
#include <hip/hip_runtime.h>
#include <cmath>

// ---------------------------------------------------------------------------
// Decoder_1898375544952: STGCN decoder (radix CSR + fp16 gather + MFMA GEMM)
//   h0 = x @ W_lin + b_lin                         [N,16]
//   h3 = relu(h0 @ Ws3 + mean_agg(h0) @ Wn3 + b3)  [N,32]
//   h2 = relu(h3 @ Ws2 + mean_agg(h3) @ Wn2 + b2)  [N,64]
//   out= sigm(h2 @ Ws1 + mean_agg(h2) @ Wn1 + b1)  [N,128]
//
// History: R11 fp16 gather 336.7. R16 partition pack-u32 + NBLK256 + merged
//   wt: 317.1 (BEST). R17 full quant: 346. R18 layer1-only quant: 324 —
//   gatherq<64> hit 44us/135MB (3rd confirmation: byte-bound) but the -20us
//   dispatch win STILL nets negative vs R16 => each added serial stage costs
//   ~5-10us of invisible inter-dispatch time. Sum of dispatch durations
//   (~215us) << total (317us): ~100us lives in ~14 serial launch gaps.
// R19: R16 exactly, minus 3 serial stages (quant dropped for good):
//   (a) prologue mega-kernel: bucket_hist (blocks 0..255) + lin16
//       (256..767) + wt_all (768..851) are independent -> 1 launch for 3;
//   (b) scan3 deleted: nblk=256 makes bcnt chunk i == bucket i's row, so
//       partition adds bsum[i] to its cursors and local_csr adds bsum[u]
//       to its segment bounds directly.
//   14 -> 11 stages. All dispatch bodies byte-identical to R16 (controls).
// ---------------------------------------------------------------------------

typedef __attribute__((ext_vector_type(8))) _Float16 half8;
typedef __attribute__((ext_vector_type(4))) float floatx4;

#define NBUCKET 512
#define BUCKET_SHIFT 8   // 256 nodes per bucket; N = 131072 = 512*256
#define WT_TOTAL 21504   // 128*128 + 64*64 + 32*32 weight elements

// ---- Prologue: bucket_hist + lin16 + wt transpose in ONE launch ----
// blocks [0, nblk): per-block bucket histogram (LDS atomics only)
// blocks [nblk, nblk+linb): h0 = x @ W_lin + b_lin (fp16 out)
// blocks [nblk+linb, ...): Wt[n][k] = (k<CI ? Ws[k][n] : Wn[k-CI][n]) fp16
__global__ __launch_bounds__(256) void prologue_kernel(
    const int* __restrict__ dst, int* __restrict__ bcnt, int E, int EPB, int nblk,
    const float* __restrict__ x, const float* __restrict__ W_lin,
    const float* __restrict__ b_lin, _Float16* __restrict__ h0, int N, int linb,
    const float* __restrict__ Ws1, const float* __restrict__ Wn1, _Float16* __restrict__ Wt1,
    const float* __restrict__ Ws2, const float* __restrict__ Wn2, _Float16* __restrict__ Wt2,
    const float* __restrict__ Ws3, const float* __restrict__ Wn3, _Float16* __restrict__ Wt3)
{
    __shared__ int lh[NBUCKET];
    __shared__ float sW[256];
    __shared__ float sb[16];
    const int bid = blockIdx.x;

    if (bid < nblk) {
        // ---- bucket histogram ----
        for (int i = threadIdx.x; i < NBUCKET; i += 256) lh[i] = 0;
        __syncthreads();
        int base = bid * EPB;
        int end  = min(base + EPB, E);
        for (int i = base + threadIdx.x; i < end; i += 256)
            atomicAdd(&lh[dst[i] >> BUCKET_SHIFT], 1);
        __syncthreads();
        for (int i = threadIdx.x; i < NBUCKET; i += 256)
            bcnt[i * nblk + bid] = lh[i];        // bucket-major
    } else if (bid < nblk + linb) {
        // ---- lin16 ----
        sW[threadIdx.x] = W_lin[threadIdx.x];
        if (threadIdx.x < 16) sb[threadIdx.x] = b_lin[threadIdx.x];
        __syncthreads();
        int n = (bid - nblk) * 256 + threadIdx.x;
        if (n >= N) return;
        const float4* xr = (const float4*)(x + (size_t)n * 16);
        float4 x0 = xr[0], x1 = xr[1], x2 = xr[2], x3 = xr[3];
        float xi[16] = {x0.x, x0.y, x0.z, x0.w, x1.x, x1.y, x1.z, x1.w,
                        x2.x, x2.y, x2.z, x2.w, x3.x, x3.y, x3.z, x3.w};
        float o[16];
#pragma unroll
        for (int j = 0; j < 16; j++) o[j] = sb[j];
#pragma unroll
        for (int k = 0; k < 16; k++) {
            float xv = xi[k];
#pragma unroll
            for (int j = 0; j < 16; j++) o[j] += xv * sW[k * 16 + j];
        }
        half8 h0v, h1v;
#pragma unroll
        for (int j = 0; j < 8; j++) { h0v[j] = (_Float16)o[j]; h1v[j] = (_Float16)o[j + 8]; }
        half8* hr = (half8*)(h0 + (size_t)n * 16);
        hr[0] = h0v;
        hr[1] = h1v;
    } else {
        // ---- weight transpose+concat ----
        int idx = (bid - nblk - linb) * 256 + threadIdx.x;
        if (idx >= WT_TOTAL) return;
        const float *Ws, *Wn; _Float16* Wt; int CI, NOUT;
        if (idx < 16384)      { Ws = Ws1; Wn = Wn1; Wt = Wt1; CI = 64; NOUT = 128; }
        else if (idx < 20480) { idx -= 16384; Ws = Ws2; Wn = Wn2; Wt = Wt2; CI = 32; NOUT = 64; }
        else                  { idx -= 20480; Ws = Ws3; Wn = Wn3; Wt = Wt3; CI = 16; NOUT = 32; }
        int K = 2 * CI;
        int n = idx / K, k = idx - n * K;
        float v = (k < CI) ? Ws[(size_t)k * NOUT + n] : Wn[(size_t)(k - CI) * NOUT + n];
        Wt[n * K + k] = (_Float16)v;
    }
}

// ---- scan helpers ----
__global__ void scan1_kernel(const int* __restrict__ in, int* __restrict__ out,
                             int* __restrict__ bsum) {
    __shared__ int s[256];
    int i = blockIdx.x * 256 + threadIdx.x;
    int v = in[i];
    s[threadIdx.x] = v;
    __syncthreads();
    for (int off = 1; off < 256; off <<= 1) {
        int t = (threadIdx.x >= off) ? s[threadIdx.x - off] : 0;
        __syncthreads();
        s[threadIdx.x] += t;
        __syncthreads();
    }
    out[i] = s[threadIdx.x] - v;
    if (threadIdx.x == 255) bsum[blockIdx.x] = s[255];
}

__global__ void scan2_kernel(int* __restrict__ bsum, int NB) {
    extern __shared__ int s2[];
    int v = (threadIdx.x < NB) ? bsum[threadIdx.x] : 0;
    s2[threadIdx.x] = v;
    __syncthreads();
    for (int off = 1; off < NB; off <<= 1) {
        int t = (threadIdx.x >= off) ? s2[threadIdx.x - off] : 0;
        __syncthreads();
        s2[threadIdx.x] += t;
        __syncthreads();
    }
    if (threadIdx.x < NB) bsum[threadIdx.x] = s2[threadIdx.x] - v;
}

// ---- Pass C: partition edges into bucket segments (LDS cursors) ----
// Packed entry: (src << 8) | (dst & 255). src < 2^24, bucket-local dst 8b.
// Folds scan3: global offset = bofs[i*nblk+b] + bsum[i] (chunk i == bucket i
// since nblk == 256).
__global__ __launch_bounds__(256) void partition_kernel(
    const int* __restrict__ src, const int* __restrict__ dst,
    const int* __restrict__ bofs, const int* __restrict__ bsum,
    int* __restrict__ part, int E, int EPB, int nblk) {
    __shared__ int cur[NBUCKET];
    for (int i = threadIdx.x; i < NBUCKET; i += 256)
        cur[i] = bofs[i * nblk + blockIdx.x] + bsum[i];
    __syncthreads();
    int base = blockIdx.x * EPB;
    int end  = min(base + EPB, E);
    for (int i = base + threadIdx.x; i < end; i += 256) {
        int d = dst[i];
        int p = atomicAdd(&cur[d >> BUCKET_SHIFT], 1);
        part[p] = (src[i] << 8) | (d & 255);
    }
}

// ---- Pass D: per-bucket local CSR (row_ptr + csr_src), all LDS-local ----
__global__ __launch_bounds__(256) void local_csr_kernel(
    const int* __restrict__ bofs, const int* __restrict__ bsum,
    const int* __restrict__ part,
    int* __restrict__ row_ptr, int* __restrict__ csr_src,
    int N, int E, int nblk) {
    __shared__ int cnt[256];
    __shared__ int offs[256];
    const int u      = blockIdx.x;
    const int node0  = u << BUCKET_SHIFT;
    const int bstart = bofs[(size_t)u * nblk] + bsum[u];
    const int bend   = (u + 1 < gridDim.x) ? bofs[(size_t)(u + 1) * nblk] + bsum[u + 1] : E;

    cnt[threadIdx.x] = 0;
    __syncthreads();
    for (int i = bstart + threadIdx.x; i < bend; i += 256)
        atomicAdd(&cnt[part[i] & 255], 1);
    __syncthreads();

    int v = cnt[threadIdx.x];
    offs[threadIdx.x] = v;
    __syncthreads();
    for (int off = 1; off < 256; off <<= 1) {
        int t = (threadIdx.x >= off) ? offs[threadIdx.x - off] : 0;
        __syncthreads();
        offs[threadIdx.x] += t;
        __syncthreads();
    }
    int excl = offs[threadIdx.x] - v;
    int rbase = bstart + excl;
    if (node0 + threadIdx.x < N) row_ptr[node0 + threadIdx.x] = rbase;
    if (u == 0 && threadIdx.x == 0) row_ptr[N] = E;
    __syncthreads();
    cnt[threadIdx.x] = rbase;       // reuse as cursor
    __syncthreads();
    for (int i = bstart + threadIdx.x; i < bend; i += 256) {
        int e = part[i];
        int p = atomicAdd(&cnt[e & 255], 1);
        csr_src[p] = e >> 8;
    }
}

// agg[n][g*8..] = (1/max(deg,1)) * sum over CSR neighbors of h[src][g*8..]
// R11 form: 8-wide unrolled rounds + single masked tail round.
template <int C>
__global__ __launch_bounds__(256) void gather_kernel(
    const int* __restrict__ row_ptr, const int* __restrict__ csr_src,
    const _Float16* __restrict__ h, _Float16* __restrict__ agg, int N) {
    constexpr int GP = C / 8;
    int t = blockIdx.x * blockDim.x + threadIdx.x;
    int total = N * GP;
    if (t >= total) return;
    int n = t / GP;
    int g = t - n * GP;
    const int beg = row_ptr[n];
    const int end = row_ptr[n + 1];
    const size_t goff = (size_t)g * 8;

    float a0[8], a1[8];
#pragma unroll
    for (int i = 0; i < 8; i++) { a0[i] = 0.f; a1[i] = 0.f; }

    int j = beg;
    for (; j + 8 <= end; j += 8) {
        int i0 = csr_src[j + 0], i1 = csr_src[j + 1], i2 = csr_src[j + 2], i3 = csr_src[j + 3];
        int i4 = csr_src[j + 4], i5 = csr_src[j + 5], i6 = csr_src[j + 6], i7 = csr_src[j + 7];
        half8 v0 = *(const half8*)(h + (size_t)i0 * C + goff);
        half8 v1 = *(const half8*)(h + (size_t)i1 * C + goff);
        half8 v2 = *(const half8*)(h + (size_t)i2 * C + goff);
        half8 v3 = *(const half8*)(h + (size_t)i3 * C + goff);
        half8 v4 = *(const half8*)(h + (size_t)i4 * C + goff);
        half8 v5 = *(const half8*)(h + (size_t)i5 * C + goff);
        half8 v6 = *(const half8*)(h + (size_t)i6 * C + goff);
        half8 v7 = *(const half8*)(h + (size_t)i7 * C + goff);
#pragma unroll
        for (int i = 0; i < 8; i++) {
            a0[i] += ((float)v0[i] + (float)v2[i]) + ((float)v4[i] + (float)v6[i]);
            a1[i] += ((float)v1[i] + (float)v3[i]) + ((float)v5[i] + (float)v7[i]);
        }
    }
    if (j < end) {
        const int last = end - 1;
        int i0 = csr_src[j];
        int i1 = csr_src[min(j + 1, last)];
        int i2 = csr_src[min(j + 2, last)];
        int i3 = csr_src[min(j + 3, last)];
        int i4 = csr_src[min(j + 4, last)];
        int i5 = csr_src[min(j + 5, last)];
        int i6 = csr_src[min(j + 6, last)];
        int i7 = csr_src[min(j + 7, last)];
        half8 v0 = *(const half8*)(h + (size_t)i0 * C + goff);
        half8 v1 = *(const half8*)(h + (size_t)i1 * C + goff);
        half8 v2 = *(const half8*)(h + (size_t)i2 * C + goff);
        half8 v3 = *(const half8*)(h + (size_t)i3 * C + goff);
        half8 v4 = *(const half8*)(h + (size_t)i4 * C + goff);
        half8 v5 = *(const half8*)(h + (size_t)i5 * C + goff);
        half8 v6 = *(const half8*)(h + (size_t)i6 * C + goff);
        half8 v7 = *(const half8*)(h + (size_t)i7 * C + goff);
        float w1 = (j + 1 < end) ? 1.f : 0.f;
        float w2 = (j + 2 < end) ? 1.f : 0.f;
        float w3 = (j + 3 < end) ? 1.f : 0.f;
        float w4 = (j + 4 < end) ? 1.f : 0.f;
        float w5 = (j + 5 < end) ? 1.f : 0.f;
        float w6 = (j + 6 < end) ? 1.f : 0.f;
        float w7 = (j + 7 < end) ? 1.f : 0.f;
#pragma unroll
        for (int i = 0; i < 8; i++) {
            a0[i] += ((float)v0[i] + w2 * (float)v2[i]) + (w4 * (float)v4[i] + w6 * (float)v6[i]);
            a1[i] += (w1 * (float)v1[i] + w3 * (float)v3[i]) + (w5 * (float)v5[i] + w7 * (float)v7[i]);
        }
    }

    float inv = 1.0f / fmaxf((float)(end - beg), 1.0f);
    half8 r;
#pragma unroll
    for (int i = 0; i < 8; i++) r[i] = (_Float16)((a0[i] + a1[i]) * inv);
    *(half8*)(agg + (size_t)n * C + goff) = r;
}

// ---- MFMA GEMM: out = act([h | a] @ Wt^T + b) with Wt[n][K] fp16 ----
// Block = 256 threads = 4 waves; wave w handles rows blockIdx.x*64 + w*16 .. +16.
// A-frag: lane m=lane&15, quad=lane>>4 reads h/a[row][s*32+quad*8 .. +8].
// B-frag: lane reads Bt[c*16+m][s*32+quad*8 .. +8] from padded LDS.
// C/D: col = c*16 + (lane&15), row = row0 + quad*4 + reg.
// ACT: 0 relu, 1 sigmoid. OUT_F16: fp16 vs fp32 output.
template <int CI, int NOUT, int ACT, bool OUT_F16>
__global__ __launch_bounds__(256) void mfma_gemm_kernel(
    const _Float16* __restrict__ hbuf, const _Float16* __restrict__ abuf,
    const _Float16* __restrict__ Wt,   // [NOUT][K] fp16
    const float* __restrict__ bias, void* __restrict__ outp, int N)
{
    constexpr int K   = 2 * CI;
    constexpr int KS  = K / 32;        // k-steps (4/2/1)
    constexpr int CT  = NOUT / 16;     // col tiles (8/4/2)
    constexpr int LDW = K + 8;         // padded LDS row (halves); LDW*2 % 16 == 0
    __shared__ _Float16 Bt[NOUT * LDW];

    const int tid = threadIdx.x;
    for (int idx = tid; idx < NOUT * (K / 8); idx += 256) {
        int n  = idx / (K / 8);
        int kq = idx - n * (K / 8);
        *(half8*)&Bt[n * LDW + kq * 8] = *(const half8*)(Wt + (size_t)n * K + kq * 8);
    }
    __syncthreads();

    const int wave = tid >> 6;
    const int lane = tid & 63;
    const int m    = lane & 15;
    const int quad = lane >> 4;
    const int row0 = blockIdx.x * 64 + wave * 16;
    const size_t row = (size_t)(row0 + m);

    floatx4 acc[CT];
#pragma unroll
    for (int c = 0; c < CT; c++) acc[c] = (floatx4){0.f, 0.f, 0.f, 0.f};

#pragma unroll
    for (int s = 0; s < KS; s++) {
        int k8 = s * 32 + quad * 8;
        const _Float16* Ap = (k8 < CI) ? (hbuf + row * CI + k8)
                                       : (abuf + row * CI + (k8 - CI));
        half8 a = *(const half8*)Ap;
#pragma unroll
        for (int c = 0; c < CT; c++) {
            half8 b = *(const half8*)&Bt[(c * 16 + m) * LDW + k8];
            acc[c] = __builtin_amdgcn_mfma_f32_16x16x32_f16(a, b, acc[c], 0, 0, 0);
        }
    }

#pragma unroll
    for (int c = 0; c < CT; c++) {
        int col = c * 16 + m;
        float bv = bias[col];
#pragma unroll
        for (int j = 0; j < 4; j++) {
            int orow = row0 + quad * 4 + j;
            float v = acc[c][j] + bv;
            if (ACT == 0) v = fmaxf(v, 0.0f);
            else          v = 1.0f / (1.0f + __expf(-v));
            if (OUT_F16) ((_Float16*)outp)[(size_t)orow * NOUT + col] = (_Float16)v;
            else         ((float*)outp)[(size_t)orow * NOUT + col] = v;
        }
    }
}

extern "C" void kernel_launch(void* const* d_in, const int* in_sizes, int n_in,
                              void* d_out, int out_size, void* d_ws, size_t ws_size,
                              hipStream_t stream) {
    const float* x     = (const float*)d_in[0];
    const int*   ei    = (const int*)d_in[1];
    // d_in[2]: batch (unused)
    const float* W_lin = (const float*)d_in[3];
    const float* b_lin = (const float*)d_in[4];
    const float* Ws3   = (const float*)d_in[5];
    const float* Wn3   = (const float*)d_in[6];
    const float* b3    = (const float*)d_in[7];
    const float* Ws2   = (const float*)d_in[8];
    const float* Wn2   = (const float*)d_in[9];
    const float* b2    = (const float*)d_in[10];
    const float* Ws1   = (const float*)d_in[11];
    const float* Wn1   = (const float*)d_in[12];
    const float* b1    = (const float*)d_in[13];
    float* out = (float*)d_out;

    const int N = in_sizes[0] / 16;
    const int E = in_sizes[1] / 2;
    const int* src = ei;
    const int* dst = ei + E;

    const int NBLK = 256;                       // partition blocks (~64B runs)
    const int EPB  = (E + NBLK - 1) / NBLK;
    const int M    = NBUCKET * NBLK;            // 131072 count entries
    const int NB2  = M / 256;                   // 512 == NBUCKET (chunk i == bucket i)

    // Workspace (ints unless noted).
    int* wsi = (int*)d_ws;
    int* row_ptr = wsi;
    size_t B0 = ((size_t)(N + 1) + 3) & ~(size_t)3;
    int* bcnt = wsi + B0;
    int* bofs = bcnt + M;
    int* bsum = bofs + M;
    size_t C0 = (B0 + 2 * (size_t)M + (size_t)NB2 + 3) & ~(size_t)3;
    int* csr_src = wsi + C0;
    size_t P0 = (C0 + (size_t)E + 3) & ~(size_t)3;
    int* part = wsi + P0;                       // E packed u32
    size_t H0 = (P0 + (size_t)E + 3) & ~(size_t)3;
    _Float16* regA = (_Float16*)(wsi + H0);
    _Float16* regB = regA + (size_t)64 * N;
    _Float16* Wt1  = regB + (size_t)64 * N;     // 128*128 = 16384 halves
    _Float16* Wt2  = Wt1 + 16384;               // 64*64   = 4096
    _Float16* Wt3  = Wt2 + 4096;                // 32*32   = 1024

    _Float16* h0    = regA;
    _Float16* agg16 = regA + (size_t)16 * N;
    _Float16* h2    = regA;                    // after h0/agg16 dead
    _Float16* h3    = regB;
    _Float16* agg32 = regB + (size_t)32 * N;
    _Float16* agg64 = regB;                    // after h3/agg32 dead

    const int BLK = 256;
    const int LINB = (N + 255) / 256;           // lin16 blocks (512)
    const int WTB  = (WT_TOTAL + 255) / 256;    // wt blocks (84)

    // ---- prologue: hist + lin16 + wt in ONE launch ----
    prologue_kernel<<<NBLK + LINB + WTB, 256, 0, stream>>>(
        dst, bcnt, E, EPB, NBLK,
        x, W_lin, b_lin, h0, N, LINB,
        Ws1, Wn1, Wt1, Ws2, Wn2, Wt2, Ws3, Wn3, Wt3);

    // ---- radix CSR build (scan3 folded into partition/local_csr) ----
    scan1_kernel<<<NB2, 256, 0, stream>>>(bcnt, bofs, bsum);
    scan2_kernel<<<1, NB2, NB2 * sizeof(int), stream>>>(bsum, NB2);
    partition_kernel<<<NBLK, 256, 0, stream>>>(src, dst, bofs, bsum, part, E, EPB, NBLK);
    local_csr_kernel<<<NBUCKET, 256, 0, stream>>>(bofs, bsum, part, row_ptr, csr_src, N, E, NBLK);

    // ---- block3: 16 -> 32, relu ----
    gather_kernel<16><<<((size_t)N * 2 + BLK - 1) / BLK, BLK, 0, stream>>>(row_ptr, csr_src, h0, agg16, N);
    mfma_gemm_kernel<16, 32, 0, true><<<N / 64, 256, 0, stream>>>(h0, agg16, Wt3, b3, h3, N);

    // ---- block2: 32 -> 64, relu ----
    gather_kernel<32><<<((size_t)N * 4 + BLK - 1) / BLK, BLK, 0, stream>>>(row_ptr, csr_src, h3, agg32, N);
    mfma_gemm_kernel<32, 64, 0, true><<<N / 64, 256, 0, stream>>>(h3, agg32, Wt2, b2, h2, N);

    // ---- block1: 64 -> 128, sigmoid -> d_out (fp32) ----
    gather_kernel<64><<<((size_t)N * 8 + BLK - 1) / BLK, BLK, 0, stream>>>(row_ptr, csr_src, h2, agg64, N);
    mfma_gemm_kernel<64, 128, 1, false><<<N / 64, 256, 0, stream>>>(h2, agg64, Wt1, b1, out, N);
}